// Round 4
// baseline (1165.895 us; speedup 1.0000x reference)
//
#include <hip/hip_runtime.h>

// Blocked-scan LRU — PURE f32 VALU bisect round (no MFMA, no bf16 anywhere).
// Purpose: decisively separate "chunk-decomposition/workspace bug" from
// "MFMA-fragment/bf16-staging bug". All per-thread idioms are copied from the
// R1 kernel that PASSED (absmax 0.0156).
//
// Shapes: NY=64 NU=32 NH=512(256 pairs) T=512 B=256. Chunk L=32, NC=16.
// Math: x[t+1] = lambda*x[t] + bu[t] (complex diagonal). Chunk L:
//   x[nL+j] = xt_j + lambda^j * xb[n],  xt = chunk-local scan from zero,
//   xb[n+1] = lambda^L * xb[n] + S_n,   S_n = xt_L of chunk n.
// K1 (4096 blk): Bu chunk via VALU (B rows in regs, U from LDS), scan -> S_n.
// K2 (256 blk):  x0 matvec, S->XB in place for n=0..15. NO slot-16 write
//                (was OOB-risk at 8.0-8.5 MB; never read anyway).
// K3 (4096 blk): Bu via VALU, scan + lambda^j correction -> A rows (f32 LDS),
//                Y[32x64] = A @ W^T via VALU partials + per-t barrier reduce.
// Workspace G: [NC][BB][256][2] f32 = exactly 8 MB.

constexpr int NY = 64, NU = 32, TT = 512, BB = 256, NC = 16, L = 32;

// ---------------- K1: chunk-local sums S_n ----------------
__global__ __launch_bounds__(256, 2)
void k1_chunk_sum(const float* __restrict__ U, const float* __restrict__ lmr,
                  const float* __restrict__ lmi, const float* __restrict__ Bm,
                  float* __restrict__ G) {
    __shared__ float us[L * NU];                     // 4 KB
    const int n = blockIdx.x >> 8, b = blockIdx.x & 255;
    const int tid = threadIdx.x;

    // stage U chunk (32 t x 32 u) as f32: 256 float4
    {
        const int row = tid >> 3, c4 = tid & 7;
        *(float4*)&us[row * NU + (c4 << 2)] =
            *(const float4*)&U[((n * L + row) * BB + b) * NU + (c4 << 2)];
    }
    // B rows in registers (R1-proven pattern)
    float Br[NU], Bi[NU];
#pragma unroll
    for (int k = 0; k < NU; ++k) {
        Br[k] = Bm[tid * NU + k];
        Bi[k] = Bm[(256 + tid) * NU + k];
    }
    const float lr = lmr[tid], li = lmi[tid];
    __syncthreads();

    float xr = 0.f, xi = 0.f;
    for (int j = 0; j < L; ++j) {
        const float* uu = &us[j * NU];
        float r0 = 0, r1 = 0, r2 = 0, r3 = 0;
        float i0 = 0, i1 = 0, i2 = 0, i3 = 0;
#pragma unroll
        for (int k = 0; k < NU; k += 4) {
            r0 += Br[k + 0] * uu[k + 0];
            r1 += Br[k + 1] * uu[k + 1];
            r2 += Br[k + 2] * uu[k + 2];
            r3 += Br[k + 3] * uu[k + 3];
            i0 += Bi[k + 0] * uu[k + 0];
            i1 += Bi[k + 1] * uu[k + 1];
            i2 += Bi[k + 2] * uu[k + 2];
            i3 += Bi[k + 3] * uu[k + 3];
        }
        const float bur = (r0 + r1) + (r2 + r3);
        const float bui = (i0 + i1) + (i2 + i3);
        const float nr = lr * xr - li * xi + bur;
        const float ni = li * xr + lr * xi + bui;
        xr = nr; xi = ni;
    }
    *(float2*)&G[((n * BB + b) * 256 + tid) * 2] = make_float2(xr, xi);
}

// ---------------- K2: boundary propagation (S->XB in place) + Y row 512 ----------------
__global__ __launch_bounds__(256, 2)
void k2_boundary(const float* __restrict__ y0, const float* __restrict__ lmr,
                 const float* __restrict__ lmi, const float* __restrict__ Wy2x,
                 const float* __restrict__ by2x, const float* __restrict__ Wx2y,
                 const float* __restrict__ bx2y, float* __restrict__ G,
                 float* __restrict__ Y) {
    __shared__ float y0s[NY];
    __shared__ float xsh[512];
    __shared__ float ps[4][NY];
    const int b = blockIdx.x, tid = threadIdx.x;
    if (tid < NY) y0s[tid] = y0[b * NY + tid];
    __syncthreads();

    // x0 = y0 @ Wy2x^T + by2x
    const float* wr = &Wy2x[tid * NY];
    const float* wi = &Wy2x[(256 + tid) * NY];
    float xr = by2x[tid], xi = by2x[256 + tid];
#pragma unroll
    for (int y = 0; y < NY; y += 4) {
        const float4 a = *(const float4*)&wr[y];
        const float4 c = *(const float4*)&wi[y];
        xr = fmaf(a.x, y0s[y], fmaf(a.y, y0s[y+1], fmaf(a.z, y0s[y+2], fmaf(a.w, y0s[y+3], xr))));
        xi = fmaf(c.x, y0s[y], fmaf(c.y, y0s[y+1], fmaf(c.z, y0s[y+2], fmaf(c.w, y0s[y+3], xi))));
    }
    // lambda^32 by repeated squaring (5x)
    float ar = lmr[tid], ai = lmi[tid];
#pragma unroll
    for (int i = 0; i < 5; ++i) { const float nr = ar*ar - ai*ai, ni = 2.f*ar*ai; ar = nr; ai = ni; }
    // propagate; G[n]: S_n -> XB_n in place. No slot-NC write (OOB-risk, unused).
    for (int nn = 0; nn < NC; ++nn) {
        const float2 s = *(const float2*)&G[((nn * BB + b) * 256 + tid) * 2];
        *(float2*)&G[((nn * BB + b) * 256 + tid) * 2] = make_float2(xr, xi);
        const float nr = fmaf(-ai, xi, fmaf(ar, xr, s.x));
        const float ni = fmaf( ar, xi, fmaf(ai, xr, s.y));
        xr = nr; xi = ni;
    }
    // xr,xi = X[512]; Y row 512 = Wx2y @ X + bias (original hidden ordering)
    xsh[tid] = xr; xsh[256 + tid] = xi;
    __syncthreads();
    const int w = tid >> 6, y = tid & 63;
    float acc = 0.f;
    const float* wrow = &Wx2y[y * 512 + w * 128];
    const float* xv = &xsh[w * 128];
#pragma unroll
    for (int k = 0; k < 128; k += 4) {
        const float4 wv = *(const float4*)&wrow[k];
        acc = fmaf(wv.x, xv[k], fmaf(wv.y, xv[k+1], fmaf(wv.z, xv[k+2], fmaf(wv.w, xv[k+3], acc))));
    }
    ps[w][y] = acc;
    __syncthreads();
    if (tid < NY)
        Y[(size_t)TT * BB * NY + b * NY + tid] =
            ps[0][tid] + ps[1][tid] + ps[2][tid] + ps[3][tid] + bx2y[tid];
}

// ---------------- K3: scan + correction + Y via VALU ----------------
__global__ __launch_bounds__(256, 2)
void k3_chunk_out(const float* __restrict__ U, const float* __restrict__ lmr,
                  const float* __restrict__ lmi, const float* __restrict__ Bm,
                  const float* __restrict__ Wx2y, const float* __restrict__ bx2y,
                  const float* __restrict__ G, float* __restrict__ Y) {
    __shared__ float As[L * 514];                    // A rows, stride 514 (8B-aligned float2 writes)
    __shared__ float us[L * NU];                     // 4 KB
    __shared__ float ps[2][4][NY];                   // double-buffered partials
    const int n = blockIdx.x >> 8, b = blockIdx.x & 255;
    const int tid = threadIdx.x;
    const int w = tid >> 6, o = tid & 63;

    {
        const int row = tid >> 3, c4 = tid & 7;
        *(float4*)&us[row * NU + (c4 << 2)] =
            *(const float4*)&U[((n * L + row) * BB + b) * NU + (c4 << 2)];
    }
    float Br[NU], Bi[NU];
#pragma unroll
    for (int k = 0; k < NU; ++k) {
        Br[k] = Bm[tid * NU + k];
        Bi[k] = Bm[(256 + tid) * NU + k];
    }
    // W chunk in registers (R1-proven): lane o, wave w -> Wx2y[o][128w..128w+128)
    float Wreg[128];
#pragma unroll
    for (int k = 0; k < 128; k += 4) {
        const float4 wv = *(const float4*)&Wx2y[o * 512 + (w << 7) + k];
        Wreg[k] = wv.x; Wreg[k+1] = wv.y; Wreg[k+2] = wv.z; Wreg[k+3] = wv.w;
    }
    const float lr = lmr[tid], li = lmi[tid];
    const float bias = bx2y[o];
    const float2 xb = *(const float2*)&G[((n * BB + b) * 256 + tid) * 2];
    __syncthreads();

    // scan: A row j (interleaved cols 2h=re, 2h+1=im) = xt_j + lambda^j * xb
    {
        float xr = 0.f, xi = 0.f, cr = xb.x, ci = xb.y;
        for (int j = 0; j < L; ++j) {
            *(float2*)&As[j * 514 + (tid << 1)] = make_float2(xr + cr, xi + ci);
            const float* uu = &us[j * NU];
            float r0 = 0, r1 = 0, r2 = 0, r3 = 0;
            float i0 = 0, i1 = 0, i2 = 0, i3 = 0;
#pragma unroll
            for (int k = 0; k < NU; k += 4) {
                r0 += Br[k + 0] * uu[k + 0];
                r1 += Br[k + 1] * uu[k + 1];
                r2 += Br[k + 2] * uu[k + 2];
                r3 += Br[k + 3] * uu[k + 3];
                i0 += Bi[k + 0] * uu[k + 0];
                i1 += Bi[k + 1] * uu[k + 1];
                i2 += Bi[k + 2] * uu[k + 2];
                i3 += Bi[k + 3] * uu[k + 3];
            }
            const float bur = (r0 + r1) + (r2 + r3);
            const float bui = (i0 + i1) + (i2 + i3);
            const float nr = lr * xr - li * xi + bur;
            const float ni = li * xr + lr * xi + bui;
            xr = nr; xi = ni;
            const float mr = fmaf(-li, ci, cr * lr);
            const float mi = fmaf( li, cr, ci * lr);
            cr = mr; ci = mi;
        }
    }
    __syncthreads();

    // Y[t][o] = sum_k A[t][k_interleaved] * W: Wreg holds original-order W[o][h];
    // interleaved col 2h <-> W[o][h], 2h+1 <-> W[o][256+h]. Wave w covers
    // original h in [64w,64w+64) (re: Wreg[0..63]... wait) -- map explicitly:
    // Wreg[k] = Wx2y[o][128w + k], k<128. Original hidden index 128w+k:
    //   if 128w+k < 256: real part of pair p=128w+k  -> interleaved col 2p
    //   else:            imag part of pair p=128w+k-256 -> col 2p+1
    for (int t = 0; t < L; ++t) {
        const float* arow = &As[t * 514];
        float p0 = 0, p1 = 0, p2 = 0, p3 = 0;
        if (w < 2) {        // original h = 128w+k in [0,256): real, col = 2*(128w+k)
            const int base = (w << 8);              // 2*128w
#pragma unroll
            for (int k = 0; k < 128; k += 4) {
                p0 += Wreg[k + 0] * arow[base + ((k + 0) << 1)];
                p1 += Wreg[k + 1] * arow[base + ((k + 1) << 1)];
                p2 += Wreg[k + 2] * arow[base + ((k + 2) << 1)];
                p3 += Wreg[k + 3] * arow[base + ((k + 3) << 1)];
            }
        } else {            // original h = 128w+k in [256,512): imag of p=h-256, col=2p+1
            const int base = ((w - 2) << 8) + 1;
#pragma unroll
            for (int k = 0; k < 128; k += 4) {
                p0 += Wreg[k + 0] * arow[base + ((k + 0) << 1)];
                p1 += Wreg[k + 1] * arow[base + ((k + 1) << 1)];
                p2 += Wreg[k + 2] * arow[base + ((k + 2) << 1)];
                p3 += Wreg[k + 3] * arow[base + ((k + 3) << 1)];
            }
        }
        ps[t & 1][w][o] = (p0 + p1) + (p2 + p3);
        __syncthreads();
        if (w == 0)
            Y[(size_t)(n * L + t) * BB * NY + (size_t)b * NY + o] =
                ps[t & 1][0][o] + ps[t & 1][1][o] + ps[t & 1][2][o] + ps[t & 1][3][o] + bias;
    }
}

extern "C" void kernel_launch(void* const* d_in, const int* in_sizes, int n_in,
                              void* d_out, int out_size, void* d_ws, size_t ws_size,
                              hipStream_t stream) {
    const float* y0   = (const float*)d_in[0];
    const float* U    = (const float*)d_in[1];
    const float* lmr  = (const float*)d_in[2];
    const float* lmi  = (const float*)d_in[3];
    const float* Bm   = (const float*)d_in[4];
    const float* Wy2x = (const float*)d_in[5];
    const float* by2x = (const float*)d_in[6];
    const float* Wx2y = (const float*)d_in[7];
    const float* bx2y = (const float*)d_in[8];
    float* Y = (float*)d_out;

    // G: [NC][BB][256][2] f32 = exactly 8 MB. No writes past 8 MB this round.
    float* G = (float*)d_ws;

    k1_chunk_sum<<<dim3(NC * BB), dim3(256), 0, stream>>>(U, lmr, lmi, Bm, G);
    k2_boundary<<<dim3(BB), dim3(256), 0, stream>>>(y0, lmr, lmi, Wy2x, by2x,
                                                    Wx2y, bx2y, G, Y);
    k3_chunk_out<<<dim3(NC * BB), dim3(256), 0, stream>>>(U, lmr, lmi, Bm,
                                                          Wx2y, bx2y, G, Y);
}

// Round 6
// 1137.330 us; speedup vs baseline: 1.0251x; 1.0251x over previous
//
#include <hip/hip_runtime.h>

// R6 — BISECT: R4's proven pure-VALU skeleton, with ONLY K1's Bu switched to
// the R5 split-bf16 MFMA path. K2/K3 are R4 verbatim (passed at 0.0156).
// If this fails (~0.4): bu_mfma/staging/scan-read is guilty.
// If this passes (~0.016): K3's Y-MFMA / A-conversion path is guilty.
//
// Shapes: NY=64 NU=32 NH=512(256 pairs) T=512 B=256. Chunk L=32, NC=16.
// Workspace G: [NC][BB][256][2] f32 = exactly 8 MB.

constexpr int NY = 64, NU = 32, TT = 512, BB = 256, NC = 16, L = 32;

typedef __attribute__((ext_vector_type(8))) short bf16x8;
typedef __attribute__((ext_vector_type(4))) float f32x4;

__device__ __forceinline__ unsigned short f2b(float f) {
    union { float f; unsigned u; } v; v.f = f;
    unsigned r = v.u + 0x7FFF + ((v.u >> 16) & 1);   // RNE
    return (unsigned short)(r >> 16);
}
__device__ __forceinline__ float b2f(unsigned short s) {
    union { unsigned u; float f; } v; v.u = ((unsigned)s) << 16; return v.f;
}
__device__ __forceinline__ void fsplit(float f, unsigned short& h, unsigned short& l) {
    h = f2b(f);
    l = f2b(f - b2f(h));
}

// Stage U chunk n (32 t-rows x 32 u) split hi/lo into ubufH/ubufL[32][40].
__device__ __forceinline__ void stage_u_bf(short* uh, short* ul,
                                           const float* __restrict__ U,
                                           int n, int b, int tid) {
    const int row = tid >> 3, c4 = tid & 7;           // 256 threads = 256 float4
    const float4 uv = *(const float4*)&U[((n * L + row) * BB + b) * NU + (c4 << 2)];
    unsigned short hx, lx, hy, ly, hz, lz, hw, lw;
    fsplit(uv.x, hx, lx); fsplit(uv.y, hy, ly);
    fsplit(uv.z, hz, lz); fsplit(uv.w, hw, lw);
    *(uint2*)&uh[row * 40 + (c4 << 2)] =
        make_uint2((unsigned)hx | ((unsigned)hy << 16), (unsigned)hz | ((unsigned)hw << 16));
    *(uint2*)&ul[row * 40 + (c4 << 2)] =
        make_uint2((unsigned)lx | ((unsigned)ly << 16), (unsigned)lz | ((unsigned)lw << 16));
}

// B fragments (interleaved cols), split hi/lo. Wave w covers n-tiles 8w..8w+7.
__device__ __forceinline__ void load_bfrag(bf16x8* bh, bf16x8* bl,
                                           const float* __restrict__ Bm,
                                           int w, int q, int c16) {
#pragma unroll
    for (int i = 0; i < 8; ++i) {
        const int nn = (((w << 3) + i) << 4) + c16;        // interleaved col 0..511
        const int rowB = ((nn & 1) << 8) + (nn >> 1);      // B row: real h / 256+h
        const float4 a = *(const float4*)&Bm[rowB * NU + (q << 3)];
        const float4 c = *(const float4*)&Bm[rowB * NU + (q << 3) + 4];
        unsigned short h, l;
        fsplit(a.x, h, l); bh[i][0] = (short)h; bl[i][0] = (short)l;
        fsplit(a.y, h, l); bh[i][1] = (short)h; bl[i][1] = (short)l;
        fsplit(a.z, h, l); bh[i][2] = (short)h; bl[i][2] = (short)l;
        fsplit(a.w, h, l); bh[i][3] = (short)h; bl[i][3] = (short)l;
        fsplit(c.x, h, l); bh[i][4] = (short)h; bl[i][4] = (short)l;
        fsplit(c.y, h, l); bh[i][5] = (short)h; bl[i][5] = (short)l;
        fsplit(c.z, h, l); bh[i][6] = (short)h; bl[i][6] = (short)l;
        fsplit(c.w, h, l); bh[i][7] = (short)h; bl[i][7] = (short)l;
    }
}

// Bu = Uchunk @ B^T, 3-term split MFMA, result split hi/lo into sbufH/sbufL.
__device__ __forceinline__ void bu_mfma(short* sH, short* sL,
                                        const short* uH, const short* uL,
                                        const bf16x8* bh, const bf16x8* bl,
                                        int w, int q, int c16) {
#pragma unroll
    for (int mt = 0; mt < 2; ++mt) {
        const bf16x8 aH = *(const bf16x8*)&uH[((mt << 4) + c16) * 40 + (q << 3)];
        const bf16x8 aL = *(const bf16x8*)&uL[((mt << 4) + c16) * 40 + (q << 3)];
#pragma unroll
        for (int i = 0; i < 8; ++i) {
            f32x4 c = {0.f, 0.f, 0.f, 0.f};
            c = __builtin_amdgcn_mfma_f32_16x16x32_bf16(aL, bh[i], c, 0, 0, 0);
            c = __builtin_amdgcn_mfma_f32_16x16x32_bf16(aH, bl[i], c, 0, 0, 0);
            c = __builtin_amdgcn_mfma_f32_16x16x32_bf16(aH, bh[i], c, 0, 0, 0);
            const int nn = (((w << 3) + i) << 4) + c16;
            const int tb = (mt << 4) + (q << 2);
#pragma unroll
            for (int r = 0; r < 4; ++r) {
                unsigned short h, l;
                fsplit(c[r], h, l);
                sH[(tb + r) * 520 + nn] = (short)h;
                sL[(tb + r) * 520 + nn] = (short)l;
            }
        }
    }
}

// ---------------- K1: chunk-local sums S_n (MFMA path under test) ----------------
__global__ __launch_bounds__(256, 2)
void k1_chunk_sum(const float* __restrict__ U, const float* __restrict__ lmr,
                  const float* __restrict__ lmi, const float* __restrict__ Bm,
                  float* __restrict__ G) {
    __shared__ short sbufH[L * 520];
    __shared__ short sbufL[L * 520];
    __shared__ short ubufH[L * 40];
    __shared__ short ubufL[L * 40];
    const int n = blockIdx.x >> 8, b = blockIdx.x & 255;
    const int tid = threadIdx.x;
    const int w = tid >> 6, lane = tid & 63, q = lane >> 4, c16 = lane & 15;

    stage_u_bf(ubufH, ubufL, U, n, b, tid);
    bf16x8 bh[8], bl[8];
    load_bfrag(bh, bl, Bm, w, q, c16);
    __syncthreads();
    bu_mfma(sbufH, sbufL, ubufH, ubufL, bh, bl, w, q, c16);
    __syncthreads();

    const float lr = lmr[tid], li = lmi[tid];
    float xr = 0.f, xi = 0.f;
#pragma unroll 8
    for (int j = 0; j < L; ++j) {
        const unsigned pH = *(const unsigned*)&sbufH[j * 520 + (tid << 1)];
        const unsigned pL = *(const unsigned*)&sbufL[j * 520 + (tid << 1)];
        const float br = b2f((unsigned short)pH) + b2f((unsigned short)pL);
        const float bi = b2f((unsigned short)(pH >> 16)) + b2f((unsigned short)(pL >> 16));
        const float nr = fmaf(-li, xi, fmaf(lr, xr, br));
        const float ni = fmaf( lr, xi, fmaf(li, xr, bi));
        xr = nr; xi = ni;
    }
    *(float2*)&G[((n * BB + b) * 256 + tid) * 2] = make_float2(xr, xi);
}

// ---------------- K2: boundary propagation + Y row 512 (R4 verbatim) ----------------
__global__ __launch_bounds__(256, 2)
void k2_boundary(const float* __restrict__ y0, const float* __restrict__ lmr,
                 const float* __restrict__ lmi, const float* __restrict__ Wy2x,
                 const float* __restrict__ by2x, const float* __restrict__ Wx2y,
                 const float* __restrict__ bx2y, float* __restrict__ G,
                 float* __restrict__ Y) {
    __shared__ float y0s[NY];
    __shared__ float xsh[512];
    __shared__ float ps[4][NY];
    const int b = blockIdx.x, tid = threadIdx.x;
    if (tid < NY) y0s[tid] = y0[b * NY + tid];
    __syncthreads();

    const float* wr = &Wy2x[tid * NY];
    const float* wi = &Wy2x[(256 + tid) * NY];
    float xr = by2x[tid], xi = by2x[256 + tid];
#pragma unroll
    for (int y = 0; y < NY; y += 4) {
        const float4 a = *(const float4*)&wr[y];
        const float4 c = *(const float4*)&wi[y];
        xr = fmaf(a.x, y0s[y], fmaf(a.y, y0s[y+1], fmaf(a.z, y0s[y+2], fmaf(a.w, y0s[y+3], xr))));
        xi = fmaf(c.x, y0s[y], fmaf(c.y, y0s[y+1], fmaf(c.z, y0s[y+2], fmaf(c.w, y0s[y+3], xi))));
    }
    float ar = lmr[tid], ai = lmi[tid];
#pragma unroll
    for (int i = 0; i < 5; ++i) { const float nr = ar*ar - ai*ai, ni = 2.f*ar*ai; ar = nr; ai = ni; }
    for (int nn = 0; nn < NC; ++nn) {
        const float2 s = *(const float2*)&G[((nn * BB + b) * 256 + tid) * 2];
        *(float2*)&G[((nn * BB + b) * 256 + tid) * 2] = make_float2(xr, xi);
        const float nr = fmaf(-ai, xi, fmaf(ar, xr, s.x));
        const float ni = fmaf( ar, xi, fmaf(ai, xr, s.y));
        xr = nr; xi = ni;
    }
    xsh[tid] = xr; xsh[256 + tid] = xi;
    __syncthreads();
    const int w = tid >> 6, y = tid & 63;
    float acc = 0.f;
    const float* wrow = &Wx2y[y * 512 + w * 128];
    const float* xv = &xsh[w * 128];
#pragma unroll
    for (int k = 0; k < 128; k += 4) {
        const float4 wv = *(const float4*)&wrow[k];
        acc = fmaf(wv.x, xv[k], fmaf(wv.y, xv[k+1], fmaf(wv.z, xv[k+2], fmaf(wv.w, xv[k+3], acc))));
    }
    ps[w][y] = acc;
    __syncthreads();
    if (tid < NY)
        Y[(size_t)TT * BB * NY + b * NY + tid] =
            ps[0][tid] + ps[1][tid] + ps[2][tid] + ps[3][tid] + bx2y[tid];
}

// ---------------- K3: scan + correction + Y via VALU (R4 verbatim) ----------------
__global__ __launch_bounds__(256, 2)
void k3_chunk_out(const float* __restrict__ U, const float* __restrict__ lmr,
                  const float* __restrict__ lmi, const float* __restrict__ Bm,
                  const float* __restrict__ Wx2y, const float* __restrict__ bx2y,
                  const float* __restrict__ G, float* __restrict__ Y) {
    __shared__ float As[L * 514];
    __shared__ float us[L * NU];
    __shared__ float ps[2][4][NY];
    const int n = blockIdx.x >> 8, b = blockIdx.x & 255;
    const int tid = threadIdx.x;
    const int w = tid >> 6, o = tid & 63;

    {
        const int row = tid >> 3, c4 = tid & 7;
        *(float4*)&us[row * NU + (c4 << 2)] =
            *(const float4*)&U[((n * L + row) * BB + b) * NU + (c4 << 2)];
    }
    float Br[NU], Bi[NU];
#pragma unroll
    for (int k = 0; k < NU; ++k) {
        Br[k] = Bm[tid * NU + k];
        Bi[k] = Bm[(256 + tid) * NU + k];
    }
    float Wreg[128];
#pragma unroll
    for (int k = 0; k < 128; k += 4) {
        const float4 wv = *(const float4*)&Wx2y[o * 512 + (w << 7) + k];
        Wreg[k] = wv.x; Wreg[k+1] = wv.y; Wreg[k+2] = wv.z; Wreg[k+3] = wv.w;
    }
    const float lr = lmr[tid], li = lmi[tid];
    const float bias = bx2y[o];
    const float2 xb = *(const float2*)&G[((n * BB + b) * 256 + tid) * 2];
    __syncthreads();

    {
        float xr = 0.f, xi = 0.f, cr = xb.x, ci = xb.y;
        for (int j = 0; j < L; ++j) {
            *(float2*)&As[j * 514 + (tid << 1)] = make_float2(xr + cr, xi + ci);
            const float* uu = &us[j * NU];
            float r0 = 0, r1 = 0, r2 = 0, r3 = 0;
            float i0 = 0, i1 = 0, i2 = 0, i3 = 0;
#pragma unroll
            for (int k = 0; k < NU; k += 4) {
                r0 += Br[k + 0] * uu[k + 0];
                r1 += Br[k + 1] * uu[k + 1];
                r2 += Br[k + 2] * uu[k + 2];
                r3 += Br[k + 3] * uu[k + 3];
                i0 += Bi[k + 0] * uu[k + 0];
                i1 += Bi[k + 1] * uu[k + 1];
                i2 += Bi[k + 2] * uu[k + 2];
                i3 += Bi[k + 3] * uu[k + 3];
            }
            const float bur = (r0 + r1) + (r2 + r3);
            const float bui = (i0 + i1) + (i2 + i3);
            const float nr = lr * xr - li * xi + bur;
            const float ni = li * xr + lr * xi + bui;
            xr = nr; xi = ni;
            const float mr = fmaf(-li, ci, cr * lr);
            const float mi = fmaf( li, cr, ci * lr);
            cr = mr; ci = mi;
        }
    }
    __syncthreads();

    for (int t = 0; t < L; ++t) {
        const float* arow = &As[t * 514];
        float p0 = 0, p1 = 0, p2 = 0, p3 = 0;
        if (w < 2) {        // original h = 128w+k in [0,256): real, col = 2*(128w+k)
            const int base = (w << 8);
#pragma unroll
            for (int k = 0; k < 128; k += 4) {
                p0 += Wreg[k + 0] * arow[base + ((k + 0) << 1)];
                p1 += Wreg[k + 1] * arow[base + ((k + 1) << 1)];
                p2 += Wreg[k + 2] * arow[base + ((k + 2) << 1)];
                p3 += Wreg[k + 3] * arow[base + ((k + 3) << 1)];
            }
        } else {            // original h = 128w+k in [256,512): imag of p=h-256, col=2p+1
            const int base = ((w - 2) << 8) + 1;
#pragma unroll
            for (int k = 0; k < 128; k += 4) {
                p0 += Wreg[k + 0] * arow[base + ((k + 0) << 1)];
                p1 += Wreg[k + 1] * arow[base + ((k + 1) << 1)];
                p2 += Wreg[k + 2] * arow[base + ((k + 2) << 1)];
                p3 += Wreg[k + 3] * arow[base + ((k + 3) << 1)];
            }
        }
        ps[t & 1][w][o] = (p0 + p1) + (p2 + p3);
        __syncthreads();
        if (w == 0)
            Y[(size_t)(n * L + t) * BB * NY + (size_t)b * NY + o] =
                ps[t & 1][0][o] + ps[t & 1][1][o] + ps[t & 1][2][o] + ps[t & 1][3][o] + bias;
    }
}

extern "C" void kernel_launch(void* const* d_in, const int* in_sizes, int n_in,
                              void* d_out, int out_size, void* d_ws, size_t ws_size,
                              hipStream_t stream) {
    const float* y0   = (const float*)d_in[0];
    const float* U    = (const float*)d_in[1];
    const float* lmr  = (const float*)d_in[2];
    const float* lmi  = (const float*)d_in[3];
    const float* Bm   = (const float*)d_in[4];
    const float* Wy2x = (const float*)d_in[5];
    const float* by2x = (const float*)d_in[6];
    const float* Wx2y = (const float*)d_in[7];
    const float* bx2y = (const float*)d_in[8];
    float* Y = (float*)d_out;

    float* G = (float*)d_ws;   // [NC][BB][256][2] f32 = exactly 8 MB

    k1_chunk_sum<<<dim3(NC * BB), dim3(256), 0, stream>>>(U, lmr, lmi, Bm, G);
    k2_boundary<<<dim3(BB), dim3(256), 0, stream>>>(y0, lmr, lmi, Wy2x, by2x,
                                                    Wx2y, bx2y, G, Y);
    k3_chunk_out<<<dim3(NC * BB), dim3(256), 0, stream>>>(U, lmr, lmi, Bm,
                                                          Wx2y, bx2y, G, Y);
}